// Round 7
// baseline (186.956 us; speedup 1.0000x reference)
//
#include <hip/hip_runtime.h>
#include <math.h>

// TopKSoftMax: rows of D=64 f32; keep top-8 (ties -> lower index, exactly as
// jax.lax.top_k), softmax over kept, zeros elsewhere.
//
// R7 = R6 with the nontemporal-store compile fix (ext_vector_type instead of
// HIP_vector_type for the builtin).
//
// Structure: persistent 2-wave blocks (10 waves/CU) + per-wave REGISTER
// prefetch. Each wave owns ONE 16 KB LDS tile (32 KB/block -> 5 blocks/CU =
// 10 waves) and prefetches tile t+1 into 64 VGPRs (16x coalesced dwordx4)
// right after staging tile t into LDS -> every wave keeps a 16 KB read burst
// in flight ~all the time; stores never drained; no __syncthreads anywhere.
// Output stores are nontemporal so the write stream doesn't evict the input
// from L3 (input L3 residency is why FETCH ~ 134 MB, not 256 MB).
//
// LDS layout (verified R4/R5): slot(r,k) = r*16 + (k ^ (r&15)), float4 units.
// All four access patterns (stage-write, row-read, writeback, out-read) hit
// each bank-quad exactly 8x per wave instruction = structural minimum.

#define D4 16
#define WAVES 2
#define THREADS (WAVES * 64)
#define TILE_F4 1024               // 64 rows x 16 float4 = 16 KB
#define MAX_WAVES 2560             // 256 CU x 10 waves

typedef float nfloat4 __attribute__((ext_vector_type(4)));

// one level of the sorted-insert chain: ti = max(ti, a); a = min(ti_old, a)
#define LVL(ti) { const float _hi = fmaxf(ti, _a); _a = fminf(ti, _a); ti = _hi; }
#define INSERT(x) { float _a = (x); \
    LVL(t0) LVL(t1) LVL(t2) LVL(t3) LVL(t4) LVL(t5) LVL(t6) \
    t7 = fmaxf(t7, _a); }

// keep if strictly > thr, or == thr while index-ordered quota remains
#define PROC(x, o) { \
    const int _kgt = ((x) > thr); \
    const int _keq = ((x) == thr) & (quota > 0); \
    quota -= _keq; \
    (o) = (_kgt | _keq) ? __expf((x) - m) * inv : 0.0f; }

__device__ __forceinline__ void topk_softmax_row(float4 (&v)[D4]) {
    float t0 = -INFINITY, t1 = -INFINITY, t2 = -INFINITY, t3 = -INFINITY,
          t4 = -INFINITY, t5 = -INFINITY, t6 = -INFINITY, t7 = -INFINITY;
    #pragma unroll
    for (int c = 0; c < D4; ++c) {
        INSERT(v[c].x) INSERT(v[c].y) INSERT(v[c].z) INSERT(v[c].w)
    }
    const float thr = t7;            // 8th order statistic
    const float m   = t0;            // row max
    int quota = 8 - ((t0 > thr) + (t1 > thr) + (t2 > thr) + (t3 > thr) +
                     (t4 > thr) + (t5 > thr) + (t6 > thr));
    const float sum = __expf(t0 - m) + __expf(t1 - m) + __expf(t2 - m) + __expf(t3 - m) +
                      __expf(t4 - m) + __expf(t5 - m) + __expf(t6 - m) + __expf(t7 - m);
    const float inv = 1.0f / sum;
    #pragma unroll
    for (int c = 0; c < D4; ++c) {
        float4 o;
        PROC(v[c].x, o.x) PROC(v[c].y, o.y) PROC(v[c].z, o.z) PROC(v[c].w, o.w)
        v[c] = o;
    }
}

__global__ __launch_bounds__(THREADS, 3)
void topk_softmax_pers(const float* __restrict__ in,
                       float* __restrict__ out,
                       int ntiles, int nwaves)
{
    __shared__ float4 buf_[WAVES][TILE_F4];   // 16 KB per wave, private

    const int lane = threadIdx.x & 63;
    const int wid  = threadIdx.x >> 6;
    float4* buf = buf_[wid];

    // contiguous tile range for this wave
    const int w = blockIdx.x * WAVES + wid;
    if (w >= nwaves) return;
    const int qt = ntiles / nwaves, rt = ntiles % nwaves;
    const int ta = w * qt + (w < rt ? w : rt);
    const int tb = ta + qt + (w < rt ? 1 : 0);
    if (ta >= tb) return;

    const float4* __restrict__ in4 = reinterpret_cast<const float4*>(in);
    float4* __restrict__ out4      = reinterpret_cast<float4*>(out);

    const int g = lane >> 4;          // row-subgroup within coalesced layout
    const int s = lane & 15;          // column-quad / swizzle key

    // ---- prologue: load tile ta into registers (coalesced 1KB/inst) ----
    float4 stage[D4];
    {
        const float4* __restrict__ p = in4 + (long long)ta * TILE_F4;
        #pragma unroll
        for (int c = 0; c < D4; ++c) stage[c] = p[c * 64 + lane];
    }

    for (int t = ta; t < tb; ++t) {
        // ---- stage regs -> LDS, swizzled: (row r, quad k) -> r*16+(k^(r&15))
        //      thread's stage[c] is flat f=c*64+lane -> r=4c+g, k=s ----
        #pragma unroll
        for (int c = 0; c < D4; ++c) {
            const int r = c * 4 + g;
            buf[r * 16 + (s ^ (r & 15))] = stage[c];
        }

        // ---- prefetch tile t+1 into regs; overlaps all compute below ----
        if (t + 1 < tb) {
            const float4* __restrict__ p = in4 + (long long)(t + 1) * TILE_F4;
            #pragma unroll
            for (int c = 0; c < D4; ++c) stage[c] = p[c * 64 + lane];
        }
        __builtin_amdgcn_sched_barrier(0);   // keep prefetch issue up here

        // ---- own row -> regs (same-wave DS is in-order; no barrier) ----
        float4 v[D4];
        #pragma unroll
        for (int c = 0; c < D4; ++c) v[c] = buf[lane * 16 + (c ^ s)];

        topk_softmax_row(v);

        // ---- writeback results to same swizzled slots ----
        #pragma unroll
        for (int c = 0; c < D4; ++c) buf[lane * 16 + (c ^ s)] = v[c];
        asm volatile("s_waitcnt lgkmcnt(0)" ::: "memory");   // cross-lane reuse

        // ---- coalesced nontemporal out: flat f=c*64+lane lives at
        //      r*16 + ((lane&15)^(r&15)), r = 4c+g ----
        float4* __restrict__ q = out4 + (long long)t * TILE_F4;
        #pragma unroll
        for (int c = 0; c < D4; ++c) {
            const int r = c * 4 + g;
            const float4 o = buf[r * 16 + (s ^ (r & 15))];
            nfloat4 no; no.x = o.x; no.y = o.y; no.z = o.z; no.w = o.w;
            __builtin_nontemporal_store(no,
                reinterpret_cast<nfloat4*>(q + c * 64 + lane));
        }
        // next iteration's stage-writes follow these out-reads in the in-order
        // per-wave DS pipe -> no WAR hazard on buf.
    }
}

// remainder rows (nrows % 64) — not taken at this problem size
__global__ __launch_bounds__(64)
void topk_softmax_tail(const float* __restrict__ in, float* __restrict__ out,
                       long long row0, long long nrows)
{
    const long long row = row0 + threadIdx.x;
    if (row >= nrows) return;
    const float4* __restrict__ p = reinterpret_cast<const float4*>(in) + row * D4;
    float4* __restrict__ q       = reinterpret_cast<float4*>(out)      + row * D4;
    float4 v[D4];
    #pragma unroll
    for (int c = 0; c < D4; ++c) v[c] = p[c];
    topk_softmax_row(v);
    #pragma unroll
    for (int c = 0; c < D4; ++c) q[c] = v[c];
}

extern "C" void kernel_launch(void* const* d_in, const int* in_sizes, int n_in,
                              void* d_out, int out_size, void* d_ws, size_t ws_size,
                              hipStream_t stream) {
    const float* in = (const float*)d_in[0];
    float* out = (float*)d_out;
    const long long nrows = in_sizes[0] / 64;
    const int ntiles = (int)(nrows / 64);
    const long long rem = nrows - (long long)ntiles * 64;

    if (ntiles > 0) {
        int nwaves = ntiles < MAX_WAVES ? ntiles : MAX_WAVES;
        const int nblocks = (nwaves + WAVES - 1) / WAVES;
        nwaves = nblocks * WAVES;   // trailing waves with empty ranges exit
        topk_softmax_pers<<<nblocks, THREADS, 0, stream>>>(in, out, ntiles, nwaves);
    }
    if (rem > 0) {
        topk_softmax_tail<<<1, 64, 0, stream>>>(in, out, (long long)ntiles * 64, nrows);
    }
}

// Round 8
// 100.577 us; speedup vs baseline: 1.8588x; 1.8588x over previous
//
#include <hip/hip_runtime.h>
#include <math.h>

// TopKSoftMax: rows of D=64 f32; keep top-8 (ties -> lower index, exactly as
// jax.lax.top_k), softmax over kept, zeros elsewhere.
//
// R8: small-tile / high-TLP version. R4 (64-row tiles, 10 waves/CU) lost ~25%
// to synchronized load->drain->compute convoys; register/vmcnt pipelining was
// defeated by the compiler twice (R5 conservative waits, R7 spill). So: 32-row
// tiles (8 KB LDS per wave, private, NO barriers) -> 16 KB/block -> 10
// blocks/CU = 20 waves/CU, 16384 independently-phased blocks. Latency hiding
// by TLP, convoy windows covered by other waves' bursts.
//
// Row split across lane pairs (l, l+32): each lane insertion-sorts top-8 of
// its 32 elements, then bitonic pair-merge via 8 shfl_xor(32):
//   c_i = max(t_i, p_{7-i})  (both lists sorted desc) == top-8 of the union.
// thr = min(c), m = max(c), denom = sum exp(c-m). Tie quota exact across the
// half boundary: first-half eq-count shuffled to the second half.
//
// LDS layout (verified R4/R5/R7): slot(r,k) = r*16 + (k ^ (r&15)), float4
// units; all access patterns at the structural bank minimum.

#define D4 16
#define ROWS 32                    // rows per wave-tile
#define TILE_F4 (ROWS * D4)        // 512 float4 = 8 KB
#define WAVES 2
#define THREADS (WAVES * 64)

// one level of the sorted-insert chain: ti = max(ti, a); a = min(ti_old, a)
#define LVL(ti) { const float _hi = fmaxf(ti, _a); _a = fminf(ti, _a); ti = _hi; }
#define INSERT(x) { float _a = (x); \
    LVL(t0) LVL(t1) LVL(t2) LVL(t3) LVL(t4) LVL(t5) LVL(t6) \
    t7 = fmaxf(t7, _a); }

// keep if strictly > thr, or == thr while index-ordered quota remains
#define PROC(x, o) { \
    const int _kgt = ((x) > thr); \
    const int _keq = ((x) == thr) & (quota > 0); \
    quota -= _keq; \
    (o) = (_kgt | _keq) ? __expf((x) - m) * inv : 0.0f; }

__device__ __forceinline__ void gload_lds16(const void* g, void* l) {
    __builtin_amdgcn_global_load_lds(
        (__attribute__((address_space(1))) void*)(g),
        (__attribute__((address_space(3))) void*)(l),
        16, 0, 0);   // 16B/lane -> global_load_lds_dwordx4
}

__global__ __launch_bounds__(THREADS)
void topk_softmax_kernel(const float* __restrict__ in,
                         float* __restrict__ out,
                         int ntiles)
{
    __shared__ float4 tile_[WAVES][TILE_F4];   // 8 KB per wave, private

    const int lane = threadIdx.x & 63;
    const int wid  = threadIdx.x >> 6;
    const int w = blockIdx.x * WAVES + wid;    // one 32-row tile per wave
    if (w >= ntiles) return;
    float4* tile = tile_[wid];

    const float4* __restrict__ p = reinterpret_cast<const float4*>(in) + (long long)w * TILE_F4;
    float4* __restrict__ q       = reinterpret_cast<float4*>(out)      + (long long)w * TILE_F4;

    const int g = lane >> 4;          // 0..3
    const int s = lane & 15;

    // ---- stage: 8x global_load_lds_dwordx4, source pre-swizzled so linear
    //      LDS dest = swizzled tile: slot r*16+(k^(r&15)) <- (row r, quad k) ----
    #pragma unroll
    for (int c = 0; c < 8; ++c) {
        const int r = c * 4 + g;                        // row of linear slot
        const int k = s ^ (r & 15);                     // quad to fetch
        gload_lds16(p + r * 16 + k, tile + c * 64);     // dst wave-uniform
    }
    asm volatile("s_waitcnt vmcnt(0)" ::: "memory");

    // ---- half-row -> regs: lane l handles elements [half*32, half*32+32) of
    //      row (lane&31); quads half*8 + c ----
    const int half = lane >> 5;       // 0: elems 0..31, 1: elems 32..63
    const int r    = lane & 31;
    const int kbase = half << 3;
    const int rk = r & 15;
    float4 v[8];
    #pragma unroll
    for (int c = 0; c < 8; ++c) v[c] = tile[r * 16 + ((kbase + c) ^ rk)];

    // ---- per-lane top-8 of 32 (sorted desc t0..t7) ----
    float t0 = -INFINITY, t1 = -INFINITY, t2 = -INFINITY, t3 = -INFINITY,
          t4 = -INFINITY, t5 = -INFINITY, t6 = -INFINITY, t7 = -INFINITY;
    #pragma unroll
    for (int c = 0; c < 8; ++c) {
        INSERT(v[c].x) INSERT(v[c].y) INSERT(v[c].z) INSERT(v[c].w)
    }

    // ---- bitonic pair-merge with partner lane (xor 32) ----
    const float p0 = __shfl_xor(t0, 32), p1 = __shfl_xor(t1, 32),
                p2 = __shfl_xor(t2, 32), p3 = __shfl_xor(t3, 32),
                p4 = __shfl_xor(t4, 32), p5 = __shfl_xor(t5, 32),
                p6 = __shfl_xor(t6, 32), p7 = __shfl_xor(t7, 32);
    const float c0 = fmaxf(t0, p7), c1 = fmaxf(t1, p6), c2 = fmaxf(t2, p5),
                c3 = fmaxf(t3, p4), c4 = fmaxf(t4, p3), c5 = fmaxf(t5, p2),
                c6 = fmaxf(t6, p1), c7 = fmaxf(t7, p0);
    // {c0..c7} == top-8 multiset of the full 64-element row (both lanes agree)
    const float m   = fmaxf(t0, p0);                       // row max
    const float thr = fminf(fminf(fminf(c0, c1), fminf(c2, c3)),
                            fminf(fminf(c4, c5), fminf(c6, c7)));  // 8th largest
    const int cnt_gt = (c0 > thr) + (c1 > thr) + (c2 > thr) + (c3 > thr) +
                       (c4 > thr) + (c5 > thr) + (c6 > thr) + (c7 > thr);
    const float sum = __expf(c0 - m) + __expf(c1 - m) + __expf(c2 - m) + __expf(c3 - m) +
                      __expf(c4 - m) + __expf(c5 - m) + __expf(c6 - m) + __expf(c7 - m);
    const float inv = 1.0f / sum;
    const int quota0 = 8 - cnt_gt;

    // ---- exact tie quota across the half boundary: first half's ==thr count ----
    int ce = 0;
    #pragma unroll
    for (int c = 0; c < 8; ++c)
        ce += (v[c].x == thr) + (v[c].y == thr) + (v[c].z == thr) + (v[c].w == thr);
    const int ce_partner = __shfl_xor(ce, 32);
    int quota = half ? (quota0 - ce_partner) : quota0;

    // ---- apply softmax in index order within the half, write back ----
    #pragma unroll
    for (int c = 0; c < 8; ++c) {
        float4 o;
        PROC(v[c].x, o.x) PROC(v[c].y, o.y) PROC(v[c].z, o.z) PROC(v[c].w, o.w)
        tile[r * 16 + ((kbase + c) ^ rk)] = o;
    }
    asm volatile("s_waitcnt lgkmcnt(0)" ::: "memory");   // cross-lane reuse below

    // ---- coalesced out: flat F=c*64+lane lives at slot r'*16+((lane&15)^(r'&15)) ----
    #pragma unroll
    for (int c = 0; c < 8; ++c) {
        const int rr = c * 4 + g;
        q[c * 64 + lane] = tile[rr * 16 + (s ^ (rr & 15))];
    }
}

// remainder rows (nrows % 32) — not taken at this problem size
__global__ __launch_bounds__(64)
void topk_softmax_tail(const float* __restrict__ in, float* __restrict__ out,
                       long long row0, long long nrows)
{
    const long long row = row0 + threadIdx.x;
    if (row >= nrows) return;
    const float4* __restrict__ p = reinterpret_cast<const float4*>(in) + row * D4;
    float4* __restrict__ q       = reinterpret_cast<float4*>(out)      + row * D4;
    float4 v[D4];
    #pragma unroll
    for (int c = 0; c < D4; ++c) v[c] = p[c];
    float t0 = -INFINITY, t1 = -INFINITY, t2 = -INFINITY, t3 = -INFINITY,
          t4 = -INFINITY, t5 = -INFINITY, t6 = -INFINITY, t7 = -INFINITY;
    #pragma unroll
    for (int c = 0; c < D4; ++c) {
        INSERT(v[c].x) INSERT(v[c].y) INSERT(v[c].z) INSERT(v[c].w)
    }
    const float thr = t7;
    const float m   = t0;
    int quota = 8 - ((t0 > thr) + (t1 > thr) + (t2 > thr) + (t3 > thr) +
                     (t4 > thr) + (t5 > thr) + (t6 > thr));
    const float sum = __expf(t0 - m) + __expf(t1 - m) + __expf(t2 - m) + __expf(t3 - m) +
                      __expf(t4 - m) + __expf(t5 - m) + __expf(t6 - m) + __expf(t7 - m);
    const float inv = 1.0f / sum;
    #pragma unroll
    for (int c = 0; c < D4; ++c) {
        float4 o;
        PROC(v[c].x, o.x) PROC(v[c].y, o.y) PROC(v[c].z, o.z) PROC(v[c].w, o.w)
        q[c] = o;
    }
}

extern "C" void kernel_launch(void* const* d_in, const int* in_sizes, int n_in,
                              void* d_out, int out_size, void* d_ws, size_t ws_size,
                              hipStream_t stream) {
    const float* in = (const float*)d_in[0];
    float* out = (float*)d_out;
    const long long nrows = in_sizes[0] / 64;
    const int ntiles = (int)(nrows / ROWS);
    const long long rem = nrows - (long long)ntiles * ROWS;

    if (ntiles > 0) {
        const int nblocks = (ntiles + WAVES - 1) / WAVES;
        topk_softmax_kernel<<<nblocks, THREADS, 0, stream>>>(in, out, ntiles);
    }
    if (rem > 0) {
        topk_softmax_tail<<<1, 64, 0, stream>>>(in, out, (long long)ntiles * ROWS, nrows);
    }
}

// Round 9
// 98.174 us; speedup vs baseline: 1.9043x; 1.0245x over previous
//
#include <hip/hip_runtime.h>
#include <math.h>

// TopKSoftMax: rows of D=64 f32; keep top-8 (ties -> lower index, exactly as
// jax.lax.top_k), softmax over kept, zeros elsewhere.
//
// R9: max-TLP version. 16-row tiles (4 KB LDS per wave, private, NO barriers),
// 4-wave blocks (16 KB) -> 8 blocks/CU = 32 waves/CU (hardware max; R8 had 20).
// __launch_bounds__(256,8) caps VGPRs at 64; the PROC pass re-reads the tile
// from LDS instead of keeping row registers live, so peak pressure ~45 regs.
//
// Row split 4-ways across lanes (l, l^16, l^32, l^48), chunk h = lane>>4:
//  - per-lane sorted-insert top-8 of its 16 elements (t0>=..>=t7)
//  - xor16 bitonic merge (c_i = max(t_i, p_{7-i}); result bitonic -> 3-stage
//    CE cleanup sorts desc)  [Batcher: max-half of a bitonic split is bitonic]
//  - xor32 max-merge -> f = top-8 multiset of the full 64-element row
//  thr = min(f), m = max, denom = sum exp(f-m).
// Tie quota exact across 4 chunks: eq-count from t-registers (saturating-safe:
// a chunk under-reports only when quota is already <=0 for later chunks in
// both accountings), prefix via shfl_xor(16/32) + selects.
//
// LDS slot(r,k) = r*16 + (k ^ r) (r<16), float4 units; stage/topk/PROC/out
// patterns each hit every bank-quad exactly 4x per wave inst = structural min.

#define D4 16
#define ROWS 16
#define TILE_F4 (ROWS * D4)        // 256 float4 = 4 KB
#define WAVES 4
#define THREADS (WAVES * 64)       // 256

// one level of the sorted-insert chain: ti = max(ti, a); a = min(ti_old, a)
#define LVL(ti) { const float _hi = fmaxf(ti, _a); _a = fminf(ti, _a); ti = _hi; }
#define INSERT(x) { float _a = (x); \
    LVL(t0) LVL(t1) LVL(t2) LVL(t3) LVL(t4) LVL(t5) LVL(t6) \
    t7 = fmaxf(t7, _a); }

// compare-exchange, max to first (desc order)
#define CE(a, b) { const float _hi = fmaxf(a, b); b = fminf(a, b); a = _hi; }

// keep if strictly > thr, or == thr while index-ordered quota remains
#define PROC(x, o) { \
    const int _kgt = ((x) > thr); \
    const int _keq = ((x) == thr) & (quota > 0); \
    quota -= _keq; \
    (o) = (_kgt | _keq) ? __expf((x) - m) * inv : 0.0f; }

__device__ __forceinline__ void gload_lds16(const void* g, void* l) {
    __builtin_amdgcn_global_load_lds(
        (__attribute__((address_space(1))) void*)(g),
        (__attribute__((address_space(3))) void*)(l),
        16, 0, 0);   // 16B/lane -> global_load_lds_dwordx4
}

__global__ __launch_bounds__(THREADS, 8)   // 8 waves/EU -> 32 waves/CU, VGPR<=64
void topk_softmax_kernel(const float* __restrict__ in,
                         float* __restrict__ out,
                         int ntiles)
{
    __shared__ float4 tile_[WAVES][TILE_F4];   // 4 KB per wave, private

    const int lane = threadIdx.x & 63;
    const int wid  = threadIdx.x >> 6;
    const int w = blockIdx.x * WAVES + wid;    // one 16-row tile per wave
    if (w >= ntiles) return;
    float4* tile = tile_[wid];

    const float4* __restrict__ p = reinterpret_cast<const float4*>(in) + (long long)w * TILE_F4;
    float4* __restrict__ q       = reinterpret_cast<float4*>(out)      + (long long)w * TILE_F4;

    const int g = lane >> 4;          // 0..3
    const int s = lane & 15;

    // ---- stage: 4x global_load_lds_dwordx4, source pre-swizzled so linear
    //      LDS dest = swizzled tile: slot r*16+(k^r) <- (row r, quad k) ----
    #pragma unroll
    for (int c = 0; c < 4; ++c) {
        const int r = c * 4 + g;                        // row of linear slot
        gload_lds16(p + r * 16 + (s ^ r), tile + c * 64);
    }
    asm volatile("s_waitcnt vmcnt(0)" ::: "memory");

    // ---- per-lane top-8 of its 16 elements: row r2, quads [4h, 4h+4) ----
    const int r2 = lane & 15;
    const int h  = lane >> 4;         // chunk index (element range h*16..h*16+15)
    const int qb = h * 4;
    float t0 = -INFINITY, t1 = -INFINITY, t2 = -INFINITY, t3 = -INFINITY,
          t4 = -INFINITY, t5 = -INFINITY, t6 = -INFINITY, t7 = -INFINITY;
    #pragma unroll
    for (int j = 0; j < 4; ++j) {
        const float4 v = tile[r2 * 16 + ((qb + j) ^ r2)];
        INSERT(v.x) INSERT(v.y) INSERT(v.z) INSERT(v.w)
    }

    // ---- merge chunks h <-> h^1 (xor16): bitonic max-merge + 3-stage sort ----
    const float pa0 = __shfl_xor(t0, 16), pa1 = __shfl_xor(t1, 16),
                pa2 = __shfl_xor(t2, 16), pa3 = __shfl_xor(t3, 16),
                pa4 = __shfl_xor(t4, 16), pa5 = __shfl_xor(t5, 16),
                pa6 = __shfl_xor(t6, 16), pa7 = __shfl_xor(t7, 16);
    float c0 = fmaxf(t0, pa7), c1 = fmaxf(t1, pa6), c2 = fmaxf(t2, pa5),
          c3 = fmaxf(t3, pa4), c4 = fmaxf(t4, pa3), c5 = fmaxf(t5, pa2),
          c6 = fmaxf(t6, pa1), c7 = fmaxf(t7, pa0);
    CE(c0, c4) CE(c1, c5) CE(c2, c6) CE(c3, c7)   // cleanup: bitonic -> desc
    CE(c0, c2) CE(c1, c3) CE(c4, c6) CE(c5, c7)
    CE(c0, c1) CE(c2, c3) CE(c4, c5) CE(c6, c7)

    // ---- merge 32 <-> 32 (xor32): top-8 multiset of the full row ----
    const float pb0 = __shfl_xor(c0, 32), pb1 = __shfl_xor(c1, 32),
                pb2 = __shfl_xor(c2, 32), pb3 = __shfl_xor(c3, 32),
                pb4 = __shfl_xor(c4, 32), pb5 = __shfl_xor(c5, 32),
                pb6 = __shfl_xor(c6, 32), pb7 = __shfl_xor(c7, 32);
    const float f0 = fmaxf(c0, pb7), f1 = fmaxf(c1, pb6), f2 = fmaxf(c2, pb5),
                f3 = fmaxf(c3, pb4), f4 = fmaxf(c4, pb3), f5 = fmaxf(c5, pb2),
                f6 = fmaxf(c6, pb1), f7 = fmaxf(c7, pb0);

    const float m   = fmaxf(c0, pb0);              // row max
    const float thr = fminf(fminf(fminf(f0, f1), fminf(f2, f3)),
                            fminf(fminf(f4, f5), fminf(f6, f7)));   // 8th largest
    const int cnt_gt = (f0 > thr) + (f1 > thr) + (f2 > thr) + (f3 > thr) +
                       (f4 > thr) + (f5 > thr) + (f6 > thr) + (f7 > thr);
    const float sum = __expf(f0 - m) + __expf(f1 - m) + __expf(f2 - m) + __expf(f3 - m) +
                      __expf(f4 - m) + __expf(f5 - m) + __expf(f6 - m) + __expf(f7 - m);
    const float inv = 1.0f / sum;

    // ---- exact tie quota: chunk eq-counts (from t regs; saturating-safe),
    //      prefix over chunks h' < h ----
    const int ce = (t0 == thr) + (t1 == thr) + (t2 == thr) + (t3 == thr) +
                   (t4 == thr) + (t5 == thr) + (t6 == thr) + (t7 == thr);
    const int e1 = __shfl_xor(ce, 16);            // ce(h^1)
    const int e2 = __shfl_xor(ce, 32);            // ce(h^2)
    const int e3 = __shfl_xor(e1, 32);            // ce(h^3)
    // absolute chunk counts
    const int a0 = (h == 0) ? ce : (h == 1) ? e1 : (h == 2) ? e2 : e3;
    const int a1 = (h == 1) ? ce : (h == 0) ? e1 : (h == 3) ? e2 : e3;
    const int a2 = (h == 2) ? ce : (h == 3) ? e1 : (h == 0) ? e2 : e3;
    const int pre = (h > 0 ? a0 : 0) + (h > 1 ? a1 : 0) + (h > 2 ? a2 : 0);
    int quota = 8 - cnt_gt - pre;

    // ---- PROC pass: re-read own quads in index order, write back in place ----
    #pragma unroll
    for (int j = 0; j < 4; ++j) {
        const int slot = r2 * 16 + ((qb + j) ^ r2);
        const float4 v = tile[slot];
        float4 o;
        PROC(v.x, o.x) PROC(v.y, o.y) PROC(v.z, o.z) PROC(v.w, o.w)
        tile[slot] = o;
    }
    asm volatile("s_waitcnt lgkmcnt(0)" ::: "memory");   // cross-lane reuse below

    // ---- coalesced out: flat F=c*64+lane lives at slot r*16+((lane&15)^r) ----
    #pragma unroll
    for (int c = 0; c < 4; ++c) {
        const int r = c * 4 + g;
        q[c * 64 + lane] = tile[r * 16 + (s ^ r)];
    }
}

// remainder rows (nrows % 16) — not taken at this problem size
__global__ __launch_bounds__(64)
void topk_softmax_tail(const float* __restrict__ in, float* __restrict__ out,
                       long long row0, long long nrows)
{
    const long long row = row0 + threadIdx.x;
    if (row >= nrows) return;
    const float4* __restrict__ p = reinterpret_cast<const float4*>(in) + row * D4;
    float4* __restrict__ q       = reinterpret_cast<float4*>(out)      + row * D4;
    float4 v[D4];
    #pragma unroll
    for (int c = 0; c < D4; ++c) v[c] = p[c];
    float t0 = -INFINITY, t1 = -INFINITY, t2 = -INFINITY, t3 = -INFINITY,
          t4 = -INFINITY, t5 = -INFINITY, t6 = -INFINITY, t7 = -INFINITY;
    #pragma unroll
    for (int c = 0; c < D4; ++c) {
        INSERT(v[c].x) INSERT(v[c].y) INSERT(v[c].z) INSERT(v[c].w)
    }
    const float thr = t7;
    const float m   = t0;
    int quota = 8 - ((t0 > thr) + (t1 > thr) + (t2 > thr) + (t3 > thr) +
                     (t4 > thr) + (t5 > thr) + (t6 > thr));
    const float sum = __expf(t0 - m) + __expf(t1 - m) + __expf(t2 - m) + __expf(t3 - m) +
                      __expf(t4 - m) + __expf(t5 - m) + __expf(t6 - m) + __expf(t7 - m);
    const float inv = 1.0f / sum;
    #pragma unroll
    for (int c = 0; c < D4; ++c) {
        float4 o;
        PROC(v[c].x, o.x) PROC(v[c].y, o.y) PROC(v[c].z, o.z) PROC(v[c].w, o.w)
        q[c] = o;
    }
}

extern "C" void kernel_launch(void* const* d_in, const int* in_sizes, int n_in,
                              void* d_out, int out_size, void* d_ws, size_t ws_size,
                              hipStream_t stream) {
    const float* in = (const float*)d_in[0];
    float* out = (float*)d_out;
    const long long nrows = in_sizes[0] / 64;
    const int ntiles = (int)(nrows / ROWS);
    const long long rem = nrows - (long long)ntiles * ROWS;

    if (ntiles > 0) {
        const int nblocks = (ntiles + WAVES - 1) / WAVES;
        topk_softmax_kernel<<<nblocks, THREADS, 0, stream>>>(in, out, ntiles);
    }
    if (rem > 0) {
        topk_softmax_tail<<<1, 64, 0, stream>>>(in, out, (long long)ntiles * ROWS, nrows);
    }
}

// Round 10
// 82.803 us; speedup vs baseline: 2.2578x; 1.1856x over previous
//
#include <hip/hip_runtime.h>
#include <math.h>

// TopKSoftMax: rows of D=64 f32; keep top-8 (ties -> lower index, exactly as
// jax.lax.top_k), softmax over kept, zeros elsewhere.
//
// R10 = R9 + NONTEMPORAL output stores (isolated A/B; R7's NT test was
// confounded by a VGPR spill). Rationale: input (256 MB) == L3 capacity; the
// allocating write stream evicts ~half of it each pass (FETCH ~131 MB). NT
// (no-allocate) writes should leave the input fully L3-resident -> FETCH -> 0,
// HBM side becomes write-dominated (fills drain pure writes at ~7 TB/s).
// Stores remain instruction-coalesced (1 KB contiguous per wave inst), so
// full-line merging should survive no-allocate.
//
// Everything else identical to R9: 16-row tiles (4 KB LDS/wave, private, no
// barriers), 4-wave blocks -> 32 waves/CU; 4-way row split with bitonic
// merges; exact tie quota; LDS slot(r,k) = r*16 + (k^r) at structural bank
// minimum for all four access patterns.

#define D4 16
#define ROWS 16
#define TILE_F4 (ROWS * D4)        // 256 float4 = 4 KB
#define WAVES 4
#define THREADS (WAVES * 64)       // 256

typedef float nfloat4 __attribute__((ext_vector_type(4)));

// one level of the sorted-insert chain: ti = max(ti, a); a = min(ti_old, a)
#define LVL(ti) { const float _hi = fmaxf(ti, _a); _a = fminf(ti, _a); ti = _hi; }
#define INSERT(x) { float _a = (x); \
    LVL(t0) LVL(t1) LVL(t2) LVL(t3) LVL(t4) LVL(t5) LVL(t6) \
    t7 = fmaxf(t7, _a); }

// compare-exchange, max to first (desc order)
#define CE(a, b) { const float _hi = fmaxf(a, b); b = fminf(a, b); a = _hi; }

// keep if strictly > thr, or == thr while index-ordered quota remains
#define PROC(x, o) { \
    const int _kgt = ((x) > thr); \
    const int _keq = ((x) == thr) & (quota > 0); \
    quota -= _keq; \
    (o) = (_kgt | _keq) ? __expf((x) - m) * inv : 0.0f; }

__device__ __forceinline__ void gload_lds16(const void* g, void* l) {
    __builtin_amdgcn_global_load_lds(
        (__attribute__((address_space(1))) void*)(g),
        (__attribute__((address_space(3))) void*)(l),
        16, 0, 0);   // 16B/lane -> global_load_lds_dwordx4
}

__global__ __launch_bounds__(THREADS, 8)   // 8 waves/EU -> 32 waves/CU
void topk_softmax_kernel(const float* __restrict__ in,
                         float* __restrict__ out,
                         int ntiles)
{
    __shared__ float4 tile_[WAVES][TILE_F4];   // 4 KB per wave, private

    const int lane = threadIdx.x & 63;
    const int wid  = threadIdx.x >> 6;
    const int w = blockIdx.x * WAVES + wid;    // one 16-row tile per wave
    if (w >= ntiles) return;
    float4* tile = tile_[wid];

    const float4* __restrict__ p = reinterpret_cast<const float4*>(in) + (long long)w * TILE_F4;
    float4* __restrict__ q       = reinterpret_cast<float4*>(out)      + (long long)w * TILE_F4;

    const int g = lane >> 4;          // 0..3
    const int s = lane & 15;

    // ---- stage: 4x global_load_lds_dwordx4, source pre-swizzled so linear
    //      LDS dest = swizzled tile: slot r*16+(k^r) <- (row r, quad k) ----
    #pragma unroll
    for (int c = 0; c < 4; ++c) {
        const int r = c * 4 + g;                        // row of linear slot
        gload_lds16(p + r * 16 + (s ^ r), tile + c * 64);
    }
    asm volatile("s_waitcnt vmcnt(0)" ::: "memory");

    // ---- per-lane top-8 of its 16 elements: row r2, quads [4h, 4h+4) ----
    const int r2 = lane & 15;
    const int h  = lane >> 4;         // chunk index (element range h*16..h*16+15)
    const int qb = h * 4;
    float t0 = -INFINITY, t1 = -INFINITY, t2 = -INFINITY, t3 = -INFINITY,
          t4 = -INFINITY, t5 = -INFINITY, t6 = -INFINITY, t7 = -INFINITY;
    #pragma unroll
    for (int j = 0; j < 4; ++j) {
        const float4 v = tile[r2 * 16 + ((qb + j) ^ r2)];
        INSERT(v.x) INSERT(v.y) INSERT(v.z) INSERT(v.w)
    }

    // ---- merge chunks h <-> h^1 (xor16): bitonic max-merge + 3-stage sort ----
    const float pa0 = __shfl_xor(t0, 16), pa1 = __shfl_xor(t1, 16),
                pa2 = __shfl_xor(t2, 16), pa3 = __shfl_xor(t3, 16),
                pa4 = __shfl_xor(t4, 16), pa5 = __shfl_xor(t5, 16),
                pa6 = __shfl_xor(t6, 16), pa7 = __shfl_xor(t7, 16);
    float c0 = fmaxf(t0, pa7), c1 = fmaxf(t1, pa6), c2 = fmaxf(t2, pa5),
          c3 = fmaxf(t3, pa4), c4 = fmaxf(t4, pa3), c5 = fmaxf(t5, pa2),
          c6 = fmaxf(t6, pa1), c7 = fmaxf(t7, pa0);
    CE(c0, c4) CE(c1, c5) CE(c2, c6) CE(c3, c7)   // cleanup: bitonic -> desc
    CE(c0, c2) CE(c1, c3) CE(c4, c6) CE(c5, c7)
    CE(c0, c1) CE(c2, c3) CE(c4, c5) CE(c6, c7)

    // ---- merge 32 <-> 32 (xor32): top-8 multiset of the full row ----
    const float pb0 = __shfl_xor(c0, 32), pb1 = __shfl_xor(c1, 32),
                pb2 = __shfl_xor(c2, 32), pb3 = __shfl_xor(c3, 32),
                pb4 = __shfl_xor(c4, 32), pb5 = __shfl_xor(c5, 32),
                pb6 = __shfl_xor(c6, 32), pb7 = __shfl_xor(c7, 32);
    const float f0 = fmaxf(c0, pb7), f1 = fmaxf(c1, pb6), f2 = fmaxf(c2, pb5),
                f3 = fmaxf(c3, pb4), f4 = fmaxf(c4, pb3), f5 = fmaxf(c5, pb2),
                f6 = fmaxf(c6, pb1), f7 = fmaxf(c7, pb0);

    const float m   = fmaxf(c0, pb0);              // row max
    const float thr = fminf(fminf(fminf(f0, f1), fminf(f2, f3)),
                            fminf(fminf(f4, f5), fminf(f6, f7)));   // 8th largest
    const int cnt_gt = (f0 > thr) + (f1 > thr) + (f2 > thr) + (f3 > thr) +
                       (f4 > thr) + (f5 > thr) + (f6 > thr) + (f7 > thr);
    const float sum = __expf(f0 - m) + __expf(f1 - m) + __expf(f2 - m) + __expf(f3 - m) +
                      __expf(f4 - m) + __expf(f5 - m) + __expf(f6 - m) + __expf(f7 - m);
    const float inv = 1.0f / sum;

    // ---- exact tie quota: chunk eq-counts (from t regs; saturating-safe),
    //      prefix over chunks h' < h ----
    const int ce = (t0 == thr) + (t1 == thr) + (t2 == thr) + (t3 == thr) +
                   (t4 == thr) + (t5 == thr) + (t6 == thr) + (t7 == thr);
    const int e1 = __shfl_xor(ce, 16);            // ce(h^1)
    const int e2 = __shfl_xor(ce, 32);            // ce(h^2)
    const int e3 = __shfl_xor(e1, 32);            // ce(h^3)
    // absolute chunk counts
    const int a0 = (h == 0) ? ce : (h == 1) ? e1 : (h == 2) ? e2 : e3;
    const int a1 = (h == 1) ? ce : (h == 0) ? e1 : (h == 3) ? e2 : e3;
    const int a2 = (h == 2) ? ce : (h == 3) ? e1 : (h == 0) ? e2 : e3;
    const int pre = (h > 0 ? a0 : 0) + (h > 1 ? a1 : 0) + (h > 2 ? a2 : 0);
    int quota = 8 - cnt_gt - pre;

    // ---- PROC pass: re-read own quads in index order, write back in place ----
    #pragma unroll
    for (int j = 0; j < 4; ++j) {
        const int slot = r2 * 16 + ((qb + j) ^ r2);
        const float4 v = tile[slot];
        float4 o;
        PROC(v.x, o.x) PROC(v.y, o.y) PROC(v.z, o.z) PROC(v.w, o.w)
        tile[slot] = o;
    }
    asm volatile("s_waitcnt lgkmcnt(0)" ::: "memory");   // cross-lane reuse below

    // ---- coalesced NT out: flat F=c*64+lane lives at slot r*16+((lane&15)^r) ----
    #pragma unroll
    for (int c = 0; c < 4; ++c) {
        const int r = c * 4 + g;
        const float4 o = tile[r * 16 + (s ^ r)];
        nfloat4 no; no.x = o.x; no.y = o.y; no.z = o.z; no.w = o.w;
        __builtin_nontemporal_store(no,
            reinterpret_cast<nfloat4*>(q + c * 64 + lane));
    }
}

// remainder rows (nrows % 16) — not taken at this problem size
__global__ __launch_bounds__(64)
void topk_softmax_tail(const float* __restrict__ in, float* __restrict__ out,
                       long long row0, long long nrows)
{
    const long long row = row0 + threadIdx.x;
    if (row >= nrows) return;
    const float4* __restrict__ p = reinterpret_cast<const float4*>(in) + row * D4;
    float4* __restrict__ q       = reinterpret_cast<float4*>(out)      + row * D4;
    float4 v[D4];
    #pragma unroll
    for (int c = 0; c < D4; ++c) v[c] = p[c];
    float t0 = -INFINITY, t1 = -INFINITY, t2 = -INFINITY, t3 = -INFINITY,
          t4 = -INFINITY, t5 = -INFINITY, t6 = -INFINITY, t7 = -INFINITY;
    #pragma unroll
    for (int c = 0; c < D4; ++c) {
        INSERT(v[c].x) INSERT(v[c].y) INSERT(v[c].z) INSERT(v[c].w)
    }
    const float thr = t7;
    const float m   = t0;
    int quota = 8 - ((t0 > thr) + (t1 > thr) + (t2 > thr) + (t3 > thr) +
                     (t4 > thr) + (t5 > thr) + (t6 > thr));
    const float sum = __expf(t0 - m) + __expf(t1 - m) + __expf(t2 - m) + __expf(t3 - m) +
                      __expf(t4 - m) + __expf(t5 - m) + __expf(t6 - m) + __expf(t7 - m);
    const float inv = 1.0f / sum;
    #pragma unroll
    for (int c = 0; c < D4; ++c) {
        float4 o;
        PROC(v[c].x, o.x) PROC(v[c].y, o.y) PROC(v[c].z, o.z) PROC(v[c].w, o.w)
        q[c] = o;
    }
}

extern "C" void kernel_launch(void* const* d_in, const int* in_sizes, int n_in,
                              void* d_out, int out_size, void* d_ws, size_t ws_size,
                              hipStream_t stream) {
    const float* in = (const float*)d_in[0];
    float* out = (float*)d_out;
    const long long nrows = in_sizes[0] / 64;
    const int ntiles = (int)(nrows / ROWS);
    const long long rem = nrows - (long long)ntiles * ROWS;

    if (ntiles > 0) {
        const int nblocks = (ntiles + WAVES - 1) / WAVES;
        topk_softmax_kernel<<<nblocks, THREADS, 0, stream>>>(in, out, ntiles);
    }
    if (rem > 0) {
        topk_softmax_tail<<<1, 64, 0, stream>>>(in, out, (long long)ntiles * ROWS, nrows);
    }
}